// Round 2
// baseline (102.348 us; speedup 1.0000x reference)
//
#include <hip/hip_runtime.h>
#include <hip/hip_bf16.h>
#include <math.h>

// Problem geometry (fixed by reference):
//   target: (8, 64, 96, 96) f32  -> (N=73728 cells, L=16 lines, 4 coords)
//   pred:   (8, 96, 96, 96) f32  -> (N, P=16 predictors, 6 fields)
// Channel stride within an image is 96*96 = 9216 floats; cells (y,x) are
// contiguous, so lane==cell gives fully coalesced per-channel loads.

#define CH_STRIDE 9216            // 96*96
#define CELLS_PER_IMG 9216
#define NCELLS (8 * 9216)         // 73728
#define NL 16

__global__ __launch_bounds__(256) void yolino_loss_kernel(
    const float* __restrict__ target,
    const float* __restrict__ pred,
    float* __restrict__ out)
{
    // Block = 256 threads = 64 cells x 4 predictor-groups.
    // Lanes within a wave map to consecutive cells -> coalesced loads.
    const int cell   = blockIdx.x * 64 + (threadIdx.x & 63);
    const int pgroup = threadIdx.x >> 6;     // 0..3, wave index in block

    const int b   = cell / CELLS_PER_IMG;
    const int rem = cell - b * CELLS_PER_IMG;   // y*96 + x

    const float* tb = target + (size_t)b * 64 * CH_STRIDE + rem;
    const float* pb = pred   + (size_t)b * 96 * CH_STRIDE + rem;

    // ---- Load all 16 target lines for this cell (64 coalesced dword loads) ----
    float tx1[NL], ty1[NL], tx2[NL], ty2[NL];
    unsigned validMask = 0;
#pragma unroll
    for (int l = 0; l < NL; ++l) {
        tx1[l] = tb[(l * 4 + 0) * CH_STRIDE];
        ty1[l] = tb[(l * 4 + 1) * CH_STRIDE];
        tx2[l] = tb[(l * 4 + 2) * CH_STRIDE];
        ty2[l] = tb[(l * 4 + 3) * CH_STRIDE];
        // tline: sum of the 4 coords > 0 (left-to-right like jnp.sum)
        float s = ((tx1[l] + ty1[l]) + tx2[l]) + ty2[l];
        if (s > 0.0f) validMask |= (1u << l);
    }

    float acc = 0.0f;

    const int p0 = pgroup * 4;
#pragma unroll
    for (int pp = 0; pp < 4; ++pp) {
        const int p = p0 + pp;
        const float px1  = pb[(p * 6 + 0) * CH_STRIDE];
        const float py1  = pb[(p * 6 + 1) * CH_STRIDE];
        const float px2  = pb[(p * 6 + 2) * CH_STRIDE];
        const float py2  = pb[(p * 6 + 3) * CH_STRIDE];
        const float conf = pb[(p * 6 + 4) * CH_STRIDE];
        const float cls  = pb[(p * 6 + 5) * CH_STRIDE];

        // Pairwise endpoint distance to each target line; track min over l.
        float dist[NL];
        float mind = 3.4e38f;
#pragma unroll
        for (int l = 0; l < NL; ++l) {
            const float dx1 = tx1[l] - px1, dy1 = ty1[l] - py1;
            const float dx2 = tx2[l] - px2, dy2 = ty2[l] - py2;
            const float d = __builtin_amdgcn_sqrtf(dx1 * dx1 + dy1 * dy1)
                          + __builtin_amdgcn_sqrtf(dx2 * dx2 + dy2 * dy2);
            dist[l] = d;
            mind = fminf(mind, d);
        }

        // ijk_mask[l] = (dist[l] == mind) && (mind < 2) && tline[l]
        // (mind >= 2  =>  thr = -1  =>  no matches, since dist >= 0)
        bool any = false;
        if (mind < 2.0f) {
            // (1 - cls_hard)^2: 1 when sigmoid(cls) <= 0.5  <=>  cls <= 0
            const float clsTerm = (cls > 0.0f) ? 0.0f : 1.0f;
#pragma unroll
            for (int l = 0; l < NL; ++l) {
                if (dist[l] == mind && ((validMask >> l) & 1u)) {
                    acc += dist[l] + clsTerm;
                    any = true;
                }
            }
        }

        // Confidence terms: (s-1)^2 if matched else s^2, s = sigmoid(conf)
        const float s = 1.0f / (1.0f + __expf(-conf));
        if (any) {
            const float d1 = s - 1.0f;
            acc += d1 * d1;
        } else {
            acc += s * s;
        }
    }

    // ---- Block reduction: wave shfl -> LDS -> single atomic per block ----
#pragma unroll
    for (int off = 32; off > 0; off >>= 1)
        acc += __shfl_down(acc, off, 64);

    __shared__ float wsum[4];
    const int lane = threadIdx.x & 63;
    const int wv   = threadIdx.x >> 6;
    if (lane == 0) wsum[wv] = acc;
    __syncthreads();
    if (threadIdx.x == 0) {
        const float total = (wsum[0] + wsum[1]) + (wsum[2] + wsum[3]);
        atomicAdd(out, total * 0.125f);   // / bs, bs = 8
    }
}

extern "C" void kernel_launch(void* const* d_in, const int* in_sizes, int n_in,
                              void* d_out, int out_size, void* d_ws, size_t ws_size,
                              hipStream_t stream) {
    const float* target = (const float*)d_in[0];
    const float* pred   = (const float*)d_in[1];
    float* out = (float*)d_out;

    // d_out is poisoned to 0xAA before every timed launch; zero it (async,
    // graph-capture safe) since we accumulate with atomics.
    hipMemsetAsync(out, 0, sizeof(float) * out_size, stream);

    const int nblocks = NCELLS / 64;   // 1152 blocks of 256 threads
    yolino_loss_kernel<<<nblocks, 256, 0, stream>>>(target, pred, out);
}

// Round 4
// 98.923 us; speedup vs baseline: 1.0346x; 1.0346x over previous
//
#include <hip/hip_runtime.h>
#include <hip/hip_bf16.h>
#include <math.h>

// Problem geometry (fixed by reference):
//   target: (8, 64, 96, 96) f32  -> (N=73728 cells, L=16 lines, 4 coords)
//   pred:   (8, 96, 96, 96) f32  -> (N, P=16 predictors, 6 fields)
// Channel stride within an image is 96*96 = 9216 floats; cells (y,x) are
// contiguous, so lane==cell gives fully coalesced per-channel loads.
//
// NOTE (session journal): round-2 bench showed dur_us=102 is dominated by the
// harness's per-iteration d_ws re-poison (256 MB fillBuffer @ ~42 us each) +
// d_in restore; our kernel is below the 41.8 us top-5 cutoff (est. ~9 us vs
// 7.5 us HBM floor). This round = falsification probe (resubmitted after an
// infra failure): kernel-side micro-opts only; if dur_us is unchanged, the
// metric is reset-bound -> roofline.

#define CH_STRIDE 9216            // 96*96
#define CELLS_PER_IMG 9216
#define NCELLS (8 * 9216)         // 73728
#define NL 16

__global__ __launch_bounds__(256) void yolino_loss_kernel(
    const float* __restrict__ target,
    const float* __restrict__ pred,
    float* __restrict__ out)
{
    // Block = 256 threads = 64 cells x 4 predictor-groups.
    // Lanes within a wave map to consecutive cells -> coalesced loads.
    const int cell   = blockIdx.x * 64 + (threadIdx.x & 63);
    const int pgroup = threadIdx.x >> 6;     // 0..3, wave index in block

    const int b   = cell / CELLS_PER_IMG;
    const int rem = cell - b * CELLS_PER_IMG;   // y*96 + x

    const float* tb = target + (size_t)b * 64 * CH_STRIDE + rem;
    const float* pb = pred   + (size_t)b * 96 * CH_STRIDE + rem;

    // ---- Issue ALL pred loads for this wave's 4 predictors up front (24
    //      coalesced dword loads) so they overlap the target loads + math ----
    const int p0 = pgroup * 4;
    float pv[4][6];
#pragma unroll
    for (int pp = 0; pp < 4; ++pp) {
#pragma unroll
        for (int k = 0; k < 6; ++k)
            pv[pp][k] = pb[((p0 + pp) * 6 + k) * CH_STRIDE];
    }

    // ---- Load all 16 target lines for this cell (64 coalesced dword loads) ----
    float tx1[NL], ty1[NL], tx2[NL], ty2[NL];
    unsigned validMask = 0;
#pragma unroll
    for (int l = 0; l < NL; ++l) {
        tx1[l] = tb[(l * 4 + 0) * CH_STRIDE];
        ty1[l] = tb[(l * 4 + 1) * CH_STRIDE];
        tx2[l] = tb[(l * 4 + 2) * CH_STRIDE];
        ty2[l] = tb[(l * 4 + 3) * CH_STRIDE];
        // tline: sum of the 4 coords > 0 (left-to-right like jnp.sum)
        float s = ((tx1[l] + ty1[l]) + tx2[l]) + ty2[l];
        if (s > 0.0f) validMask |= (1u << l);
    }

    float acc = 0.0f;

#pragma unroll
    for (int pp = 0; pp < 4; ++pp) {
        const float px1  = pv[pp][0];
        const float py1  = pv[pp][1];
        const float px2  = pv[pp][2];
        const float py2  = pv[pp][3];
        const float conf = pv[pp][4];
        const float cls  = pv[pp][5];

        // Pairwise endpoint distance to each target line.
        float dist[NL];
#pragma unroll
        for (int l = 0; l < NL; ++l) {
            const float dx1 = tx1[l] - px1, dy1 = ty1[l] - py1;
            const float dx2 = tx2[l] - px2, dy2 = ty2[l] - py2;
            dist[l] = __builtin_amdgcn_sqrtf(fmaf(dx1, dx1, dy1 * dy1))
                    + __builtin_amdgcn_sqrtf(fmaf(dx2, dx2, dy2 * dy2));
        }

        // Tree min over 16 (fuses to v_min3_f32, breaks the serial dep chain)
        float m01 = fminf(fminf(dist[0],  dist[1]),  dist[2]);
        float m23 = fminf(fminf(dist[3],  dist[4]),  dist[5]);
        float m45 = fminf(fminf(dist[6],  dist[7]),  dist[8]);
        float m67 = fminf(fminf(dist[9],  dist[10]), dist[11]);
        float m89 = fminf(fminf(dist[12], dist[13]), dist[14]);
        float mind = fminf(fminf(fminf(m01, m23), fminf(m45, m67)),
                           fminf(m89, dist[15]));

        // ijk_mask[l] = (dist[l] == mind) && (mind < 2) && tline[l]
        // (mind >= 2  =>  thr = -1  =>  no matches, since dist >= 0)
        bool any = false;
        if (mind < 2.0f) {
            // (1 - cls_hard)^2: 1 when sigmoid(cls) <= 0.5  <=>  cls <= 0
            const float clsTerm = (cls > 0.0f) ? 0.0f : 1.0f;
#pragma unroll
            for (int l = 0; l < NL; ++l) {
                if (dist[l] == mind && ((validMask >> l) & 1u)) {
                    acc += dist[l] + clsTerm;
                    any = true;
                }
            }
        }

        // Confidence terms: (s-1)^2 if matched else s^2, s = sigmoid(conf)
        const float s = 1.0f / (1.0f + __expf(-conf));
        if (any) {
            const float d1 = s - 1.0f;
            acc += d1 * d1;
        } else {
            acc += s * s;
        }
    }

    // ---- Block reduction: wave shfl -> LDS -> single atomic per block ----
#pragma unroll
    for (int off = 32; off > 0; off >>= 1)
        acc += __shfl_down(acc, off, 64);

    __shared__ float wsum[4];
    const int lane = threadIdx.x & 63;
    const int wv   = threadIdx.x >> 6;
    if (lane == 0) wsum[wv] = acc;
    __syncthreads();
    if (threadIdx.x == 0) {
        const float total = (wsum[0] + wsum[1]) + (wsum[2] + wsum[3]);
        atomicAdd(out, total * 0.125f);   // / bs, bs = 8
    }
}

extern "C" void kernel_launch(void* const* d_in, const int* in_sizes, int n_in,
                              void* d_out, int out_size, void* d_ws, size_t ws_size,
                              hipStream_t stream) {
    const float* target = (const float*)d_in[0];
    const float* pred   = (const float*)d_in[1];
    float* out = (float*)d_out;

    // d_out is poisoned to 0xAA before every timed launch; zero it (async,
    // graph-capture safe) since we accumulate with atomics.
    hipMemsetAsync(out, 0, sizeof(float) * out_size, stream);

    const int nblocks = NCELLS / 64;   // 1152 blocks of 256 threads
    yolino_loss_kernel<<<nblocks, 256, 0, stream>>>(target, pred, out);
}